// Round 6
// baseline (907.316 us; speedup 1.0000x reference)
//
#include <hip/hip_runtime.h>

#define NPIX 16384   // 128*128
#define BATCH 8

// ---------------- prep: fold bn(1e-5) into reduce weights + transpose
// wrpT[s][m][c] = wd_red[s][c][m] * scd(s,c);  bp[s][c] = sb - sm*scd
__global__ void prep_kernel(const float* __restrict__ wred5,   // (5,64,64)
                            const float* __restrict__ sg5, const float* __restrict__ sb5,
                            const float* __restrict__ sm5, const float* __restrict__ sv5,
                            float* __restrict__ wrpT,          // (5,64,64) [s][m][c]
                            float* __restrict__ bp) {          // (5,64)
    int t = blockIdx.x * blockDim.x + threadIdx.x;             // 20480 threads
    if (t >= 5 * 64 * 64) return;
    int s = t >> 12;
    int m = (t >> 6) & 63;
    int c = t & 63;
    int sc_i = s * 64 + c;
    float scd = sg5[sc_i] * rsqrtf(sv5[sc_i] + 1e-5f);
    wrpT[(size_t)s * 4096 + m * 64 + c] = wred5[(size_t)s * 4096 + c * 64 + m] * scd;
    if (m == 0) bp[sc_i] = sb5[sc_i] - sm5[sc_i] * scd;
}

// ---------------- stage-1 kernel generation with fused 2x2 avg-pool
// x (B,32,256,256) -> k1 (B,9,128,128)            [proven]
__global__ void kgen1_kernel(const float* __restrict__ x,
                             const float* __restrict__ w_red,   // (32,32)
                             const float* __restrict__ g,
                             const float* __restrict__ bta,
                             const float* __restrict__ mn,
                             const float* __restrict__ vr,
                             const float* __restrict__ w_span,  // (9,32)
                             float* __restrict__ kout) {
    int t = blockIdx.x * blockDim.x + threadIdx.x;        // B*NPIX threads
    int b = t >> 14;
    int pix = t & (NPIX - 1);
    int j = pix & 127, i = pix >> 7;
    float inv[32];
    const float* xb = x + ((size_t)b * 32) * 65536 + (size_t)(2 * i) * 256 + 2 * j;
#pragma unroll
    for (int m = 0; m < 32; ++m) {
        const float2* r0 = (const float2*)(xb + (size_t)m * 65536);
        const float2* r1 = (const float2*)(xb + (size_t)m * 65536 + 256);
        float2 a = r0[0], bb = r1[0];
        inv[m] = 0.25f * ((a.x + a.y) + (bb.x + bb.y));
    }
    float kacc[9];
#pragma unroll
    for (int r = 0; r < 9; ++r) kacc[r] = 0.f;
    for (int c = 0; c < 32; ++c) {
        float a0 = 0.f, a1 = 0.f, a2 = 0.f, a3 = 0.f;
#pragma unroll
        for (int m = 0; m < 32; m += 4) {
            a0 = fmaf(w_red[c * 32 + m + 0], inv[m + 0], a0);
            a1 = fmaf(w_red[c * 32 + m + 1], inv[m + 1], a1);
            a2 = fmaf(w_red[c * 32 + m + 2], inv[m + 2], a2);
            a3 = fmaf(w_red[c * 32 + m + 3], inv[m + 3], a3);
        }
        float acc = (a0 + a1) + (a2 + a3);
        float sc = g[c] * rsqrtf(vr[c] + 1e-5f);
        float tt = (acc - mn[c]) * sc + bta[c];
        tt = tt > 0.f ? tt : 0.f;
#pragma unroll
        for (int r = 0; r < 9; ++r) kacc[r] = fmaf(w_span[r * 32 + c], tt, kacc[r]);
    }
    float* ko = kout + ((size_t)b * 9) * NPIX + pix;
#pragma unroll
    for (int r = 0; r < 9; ++r) ko[(size_t)r * NPIX] = kacc[r];
}

// ---------------- fused involution-apply + 1x1 conv 32->64 + bn + prelu [proven]
__global__ void applyconv_kernel(const float* __restrict__ x,
                                 const float* __restrict__ kb,   // (B,9,NPIX)
                                 const float* __restrict__ w,    // (64,32) w1_init
                                 const float* __restrict__ g, const float* __restrict__ bt,
                                 const float* __restrict__ mn, const float* __restrict__ vr,
                                 const float* __restrict__ pr,
                                 float* __restrict__ o1) {
    __shared__ float lds_p[64][33];
    int lane = threadIdx.x & 63;
    int q = threadIdx.x >> 6;              // wave id 0..3
    int gp = blockIdx.x * 64 + lane;       // global pixel id (64 px per block)
    int b = gp >> 14;
    int pix = gp & (NPIX - 1);
    int i = pix >> 7, j = pix & 127;
    const float* xb = x + ((size_t)b * 32) * 65536;

    float k1[9];
    const float* kp = kb + ((size_t)b * 9) * NPIX + pix;
#pragma unroll
    for (int r = 0; r < 9; ++r) k1[r] = kp[(size_t)r * NPIX];

    int y0 = 2 * i - 1;
    int coff = (j == 0) ? 0 : (2 * j - 2);
#pragma unroll
    for (int mg = 0; mg < 8; mg += 2) {
        float2 lo[2][3], hi[2][3];
#pragma unroll
        for (int mm = 0; mm < 2; ++mm) {
            const float* cb = xb + (size_t)(8 * q + mg + mm) * 65536;
#pragma unroll
            for (int ky = 0; ky < 3; ++ky) {
                int y = y0 + ky;
                int yc = y < 0 ? 0 : y;
                const float* row = cb + (size_t)yc * 256;
                lo[mm][ky] = *(const float2*)(row + coff);
                hi[mm][ky] = *(const float2*)(row + 2 * j);
            }
        }
#pragma unroll
        for (int mm = 0; mm < 2; ++mm) {
            float acc = 0.f;
#pragma unroll
            for (int ky = 0; ky < 3; ++ky) {
                int y = y0 + ky;
                float t0 = (j == 0) ? 0.f : lo[mm][ky].y;
                float t1 = hi[mm][ky].x;
                float t2 = hi[mm][ky].y;
                if (y < 0) { t0 = 0.f; t1 = 0.f; t2 = 0.f; }
                acc = fmaf(k1[3 * ky + 0], t0, acc);
                acc = fmaf(k1[3 * ky + 1], t1, acc);
                acc = fmaf(k1[3 * ky + 2], t2, acc);
            }
            lds_p[lane][8 * q + mg + mm] = acc;
        }
    }
    __syncthreads();

    float pv[32];
#pragma unroll
    for (int m = 0; m < 32; ++m) pv[m] = lds_p[lane][m];
    float* ob = o1 + ((size_t)b * 64) * NPIX + pix;
#pragma unroll
    for (int cc = 0; cc < 16; ++cc) {
        int c = 16 * q + cc;
        const float* wc = w + c * 32;
        float a0 = 0.f, a1 = 0.f, a2 = 0.f, a3 = 0.f;
#pragma unroll
        for (int m = 0; m < 32; m += 4) {
            float4 w4 = *(const float4*)(wc + m);
            a0 = fmaf(w4.x, pv[m + 0], a0);
            a1 = fmaf(w4.y, pv[m + 1], a1);
            a2 = fmaf(w4.z, pv[m + 2], a2);
            a3 = fmaf(w4.w, pv[m + 3], a3);
        }
        float sc = g[c] * rsqrtf(vr[c] + 1e-3f);
        float v = ((a0 + a1) + (a2 + a3) - mn[c]) * sc + bt[c];
        v = v > 0.f ? v : pr[c] * v;
        ob[(size_t)c * NPIX] = v;
    }
}

// ---------------- fused dilated stage: kgen + involution-apply + bn + prelu
// Block = (stage s, batch b, 64-px half-row); thread = (pixel lane, c-quarter q).
// Phase 1: stream o1's 64 channels, acc[16] per thread (bn pre-folded weights),
//          relu, span partials, cross-wave LDS reduce -> k[9] per pixel.
// Phase 2: 9-tap dilated involution for the thread's 16 channels + bnd/prelu +
//          bnf/prelu, direct store. No k5 buffer, no apply5 kernel.
__global__ void dstage_kernel(const float* __restrict__ o1,
                              const float* __restrict__ wrpT,   // (5,64,64) [s][m][c]
                              const float* __restrict__ bp,     // (5,64)
                              const float* __restrict__ wspan5, // (5,9,64)
                              const float* __restrict__ gd5, const float* __restrict__ bd5,
                              const float* __restrict__ md5, const float* __restrict__ vd5,
                              const float* __restrict__ ad5,
                              const float* __restrict__ gf, const float* __restrict__ bf,
                              const float* __restrict__ mf, const float* __restrict__ vf,
                              const float* __restrict__ af,
                              float* __restrict__ out) {
    __shared__ float pk_lds[9][4][66];     // [r][q][lane] — conflict-free both ways
    int blk = blockIdx.x;                  // 10240 = 8 XCD chunks * 1280
    int v = (blk & 7) * 1280 + (blk >> 3); // contiguous v within an XCD
    int s = v >> 11;                       // stage 0..4
    int b = (v >> 8) & 7;
    int chunk = v & 255;                   // 64-px half-row
    int i = chunk >> 1;                    // block-uniform row
    int lane = threadIdx.x & 63;
    int q = threadIdx.x >> 6;              // c-quarter 0..3
    int j = ((chunk & 1) << 6) + lane;
    int pix = i * 128 + j;
    const float* ob = o1 + ((size_t)b * 64) * NPIX + pix;

    // ---- phase 1: acc[16] = bp + sum_m wrpT[m][c]*o1[m]  (streamed)
    float acc[16];
    {
        const float* bpc = bp + s * 64 + 16 * q;
        float4 b0 = *(const float4*)(bpc + 0);
        float4 b1 = *(const float4*)(bpc + 4);
        float4 b2 = *(const float4*)(bpc + 8);
        float4 b3 = *(const float4*)(bpc + 12);
        acc[0] = b0.x; acc[1] = b0.y; acc[2] = b0.z; acc[3] = b0.w;
        acc[4] = b1.x; acc[5] = b1.y; acc[6] = b1.z; acc[7] = b1.w;
        acc[8] = b2.x; acc[9] = b2.y; acc[10] = b2.z; acc[11] = b2.w;
        acc[12] = b3.x; acc[13] = b3.y; acc[14] = b3.z; acc[15] = b3.w;
    }
    const float* wT = wrpT + (size_t)s * 4096 + 16 * q;
#pragma unroll 8
    for (int m = 0; m < 64; ++m) {
        float vv = ob[(size_t)m * NPIX];
        const float* wm = wT + m * 64;
        float4 w0 = *(const float4*)(wm + 0);
        float4 w1 = *(const float4*)(wm + 4);
        float4 w2 = *(const float4*)(wm + 8);
        float4 w3 = *(const float4*)(wm + 12);
        acc[0]  = fmaf(w0.x, vv, acc[0]);  acc[1]  = fmaf(w0.y, vv, acc[1]);
        acc[2]  = fmaf(w0.z, vv, acc[2]);  acc[3]  = fmaf(w0.w, vv, acc[3]);
        acc[4]  = fmaf(w1.x, vv, acc[4]);  acc[5]  = fmaf(w1.y, vv, acc[5]);
        acc[6]  = fmaf(w1.z, vv, acc[6]);  acc[7]  = fmaf(w1.w, vv, acc[7]);
        acc[8]  = fmaf(w2.x, vv, acc[8]);  acc[9]  = fmaf(w2.y, vv, acc[9]);
        acc[10] = fmaf(w2.z, vv, acc[10]); acc[11] = fmaf(w2.w, vv, acc[11]);
        acc[12] = fmaf(w3.x, vv, acc[12]); acc[13] = fmaf(w3.y, vv, acc[13]);
        acc[14] = fmaf(w3.z, vv, acc[14]); acc[15] = fmaf(w3.w, vv, acc[15]);
    }
    // relu
#pragma unroll
    for (int cc = 0; cc < 16; ++cc) acc[cc] = acc[cc] > 0.f ? acc[cc] : 0.f;

    // span partials over this quarter's 16 channels
    const float* wsp_s = wspan5 + s * 576 + 16 * q;
#pragma unroll
    for (int r = 0; r < 9; ++r) {
        const float* wr_ = wsp_s + r * 64;
        float4 w0 = *(const float4*)(wr_ + 0);
        float4 w1 = *(const float4*)(wr_ + 4);
        float4 w2 = *(const float4*)(wr_ + 8);
        float4 w3 = *(const float4*)(wr_ + 12);
        float p0 = fmaf(w0.x, acc[0], fmaf(w0.y, acc[1], fmaf(w0.z, acc[2], w0.w * acc[3])));
        float p1 = fmaf(w1.x, acc[4], fmaf(w1.y, acc[5], fmaf(w1.z, acc[6], w1.w * acc[7])));
        float p2 = fmaf(w2.x, acc[8], fmaf(w2.y, acc[9], fmaf(w2.z, acc[10], w2.w * acc[11])));
        float p3 = fmaf(w3.x, acc[12], fmaf(w3.y, acc[13], fmaf(w3.z, acc[14], w3.w * acc[15])));
        pk_lds[r][q][lane] = (p0 + p1) + (p2 + p3);
    }
    __syncthreads();

    // full k[9] per pixel
    float k[9];
#pragma unroll
    for (int r = 0; r < 9; ++r)
        k[r] = (pk_lds[r][0][lane] + pk_lds[r][1][lane]) +
               (pk_lds[r][2][lane] + pk_lds[r][3][lane]);

    // ---- phase 2: dilated 9-tap involution for this thread's 16 channels
    int dil = 1 << s;
    float oacc[16];
#pragma unroll
    for (int cc = 0; cc < 16; ++cc) oacc[cc] = 0.f;
    const float* cb = o1 + ((size_t)(b * 64 + 16 * q)) * NPIX;
#pragma unroll
    for (int ky = 0; ky < 3; ++ky) {
        int y = i + dil * (ky - 1);
        if ((unsigned)y >= 128u) continue;             // block-uniform skip
        const float* rowb = cb + (size_t)y * 128;
#pragma unroll
        for (int kx = 0; kx < 3; ++kx) {
            int xx = j + dil * (kx - 1);
            bool ok = (unsigned)xx < 128u;
            int xc = ok ? xx : j;                      // safe in-row address
            float kt = k[3 * ky + kx];
#pragma unroll
            for (int cc = 0; cc < 16; ++cc) {
                float vv = rowb[(size_t)cc * NPIX + xc];
                vv = ok ? vv : 0.f;
                oacc[cc] = fmaf(kt, vv, oacc[cc]);
            }
        }
    }

    // bnd(1e-3)+prelu then bnf(1e-3)+prelu, direct store
    float* outb = out + ((size_t)(b * 320 + s * 64 + 16 * q)) * NPIX + pix;
#pragma unroll
    for (int cc = 0; cc < 16; ++cc) {
        int sc_i = s * 64 + 16 * q + cc;
        float scd = gd5[sc_i] * rsqrtf(vd5[sc_i] + 1e-3f);
        float scf = gf[sc_i] * rsqrtf(vf[sc_i] + 1e-3f);
        float vv = (oacc[cc] - md5[sc_i]) * scd + bd5[sc_i];
        vv = vv > 0.f ? vv : ad5[sc_i] * vv;
        vv = (vv - mf[sc_i]) * scf + bf[sc_i];
        vv = vv > 0.f ? vv : af[sc_i] * vv;
        outb[(size_t)cc * NPIX] = vv;
    }
}

extern "C" void kernel_launch(void* const* d_in, const int* in_sizes, int n_in,
                              void* d_out, int out_size, void* d_ws, size_t ws_size,
                              hipStream_t stream) {
    const float* x       = (const float*)d_in[0];
    const float* w1_init = (const float*)d_in[1];
    const float* w1_red  = (const float*)d_in[2];
    const float* s1_g    = (const float*)d_in[3];
    const float* s1_b    = (const float*)d_in[4];
    const float* s1_m    = (const float*)d_in[5];
    const float* s1_v    = (const float*)d_in[6];
    const float* w1_span = (const float*)d_in[7];
    const float* bn1_g   = (const float*)d_in[8];
    const float* bn1_b   = (const float*)d_in[9];
    const float* bn1_m   = (const float*)d_in[10];
    const float* bn1_v   = (const float*)d_in[11];
    const float* pr1     = (const float*)d_in[12];
    const float* wd_red  = (const float*)d_in[13];  // (5,64,64)
    const float* sd_g    = (const float*)d_in[14];
    const float* sd_b    = (const float*)d_in[15];
    const float* sd_m    = (const float*)d_in[16];
    const float* sd_v    = (const float*)d_in[17];
    const float* wd_span = (const float*)d_in[18];  // (5,9,64)
    const float* bnd_g   = (const float*)d_in[19];
    const float* bnd_b   = (const float*)d_in[20];
    const float* bnd_m   = (const float*)d_in[21];
    const float* bnd_v   = (const float*)d_in[22];
    const float* prd     = (const float*)d_in[23];
    const float* bnf_g   = (const float*)d_in[24];
    const float* bnf_b   = (const float*)d_in[25];
    const float* bnf_m   = (const float*)d_in[26];
    const float* bnf_v   = (const float*)d_in[27];
    const float* prf     = (const float*)d_in[28];
    float* out = (float*)d_out;

    float* ws    = (float*)d_ws;
    float* o1buf = ws + 64;
    float* k1buf = o1buf + 8388608;            // 8*64*16384
    float* wrpT  = k1buf + 1179648;            // 8*9*16384
    float* bpbuf = wrpT + 20480;               // 5*64*64

    const int TB = 256;

    hipLaunchKernelGGL(prep_kernel, dim3(80), dim3(TB), 0, stream,
                       wd_red, sd_g, sd_b, sd_m, sd_v, wrpT, bpbuf);
    hipLaunchKernelGGL(kgen1_kernel, dim3(BATCH * NPIX / TB), dim3(TB), 0, stream,
                       x, w1_red, s1_g, s1_b, s1_m, s1_v, w1_span, k1buf);
    hipLaunchKernelGGL(applyconv_kernel, dim3(2048), dim3(TB), 0, stream,
                       x, k1buf, w1_init, bn1_g, bn1_b, bn1_m, bn1_v, pr1, o1buf);
    hipLaunchKernelGGL(dstage_kernel, dim3(10240), dim3(TB), 0, stream,
                       o1buf, wrpT, bpbuf, wd_span,
                       bnd_g, bnd_b, bnd_m, bnd_v, prd,
                       bnf_g, bnf_b, bnf_m, bnf_v, prf,
                       out);
}

// Round 7
// 762.420 us; speedup vs baseline: 1.1900x; 1.1900x over previous
//
#include <hip/hip_runtime.h>

#define NPIX 16384   // 128*128
#define BATCH 8

// ---------------- prep: fold bn(1e-5) into reduce weights + transpose
// wrpT[s][m][c] = wd_red[s][c][m] * scd(s,c);  bp[s][c] = sb - sm*scd
__global__ void prep_kernel(const float* __restrict__ wred5,   // (5,64,64)
                            const float* __restrict__ sg5, const float* __restrict__ sb5,
                            const float* __restrict__ sm5, const float* __restrict__ sv5,
                            float* __restrict__ wrpT,          // (5,64,64) [s][m][c]
                            float* __restrict__ bp) {          // (5,64)
    int t = blockIdx.x * blockDim.x + threadIdx.x;
    if (t >= 5 * 64 * 64) return;
    int s = t >> 12;
    int m = (t >> 6) & 63;
    int c = t & 63;
    int sc_i = s * 64 + c;
    float scd = sg5[sc_i] * rsqrtf(sv5[sc_i] + 1e-5f);
    wrpT[(size_t)s * 4096 + m * 64 + c] = wred5[(size_t)s * 4096 + c * 64 + m] * scd;
    if (m == 0) bp[sc_i] = sb5[sc_i] - sm5[sc_i] * scd;
}

// ---------------- stage-1 kernel generation with fused 2x2 avg-pool [proven]
__global__ void kgen1_kernel(const float* __restrict__ x,
                             const float* __restrict__ w_red,   // (32,32)
                             const float* __restrict__ g,
                             const float* __restrict__ bta,
                             const float* __restrict__ mn,
                             const float* __restrict__ vr,
                             const float* __restrict__ w_span,  // (9,32)
                             float* __restrict__ kout) {
    int t = blockIdx.x * blockDim.x + threadIdx.x;        // B*NPIX threads
    int b = t >> 14;
    int pix = t & (NPIX - 1);
    int j = pix & 127, i = pix >> 7;
    float inv[32];
    const float* xb = x + ((size_t)b * 32) * 65536 + (size_t)(2 * i) * 256 + 2 * j;
#pragma unroll
    for (int m = 0; m < 32; ++m) {
        const float2* r0 = (const float2*)(xb + (size_t)m * 65536);
        const float2* r1 = (const float2*)(xb + (size_t)m * 65536 + 256);
        float2 a = r0[0], bb = r1[0];
        inv[m] = 0.25f * ((a.x + a.y) + (bb.x + bb.y));
    }
    float kacc[9];
#pragma unroll
    for (int r = 0; r < 9; ++r) kacc[r] = 0.f;
    for (int c = 0; c < 32; ++c) {
        float a0 = 0.f, a1 = 0.f, a2 = 0.f, a3 = 0.f;
#pragma unroll
        for (int m = 0; m < 32; m += 4) {
            a0 = fmaf(w_red[c * 32 + m + 0], inv[m + 0], a0);
            a1 = fmaf(w_red[c * 32 + m + 1], inv[m + 1], a1);
            a2 = fmaf(w_red[c * 32 + m + 2], inv[m + 2], a2);
            a3 = fmaf(w_red[c * 32 + m + 3], inv[m + 3], a3);
        }
        float acc = (a0 + a1) + (a2 + a3);
        float sc = g[c] * rsqrtf(vr[c] + 1e-5f);
        float tt = (acc - mn[c]) * sc + bta[c];
        tt = tt > 0.f ? tt : 0.f;
#pragma unroll
        for (int r = 0; r < 9; ++r) kacc[r] = fmaf(w_span[r * 32 + c], tt, kacc[r]);
    }
    float* ko = kout + ((size_t)b * 9) * NPIX + pix;
#pragma unroll
    for (int r = 0; r < 9; ++r) ko[(size_t)r * NPIX] = kacc[r];
}

// ---------------- fused involution-apply + 1x1 conv 32->64 + bn + prelu [proven]
__global__ void applyconv_kernel(const float* __restrict__ x,
                                 const float* __restrict__ kb,   // (B,9,NPIX)
                                 const float* __restrict__ w,    // (64,32) w1_init
                                 const float* __restrict__ g, const float* __restrict__ bt,
                                 const float* __restrict__ mn, const float* __restrict__ vr,
                                 const float* __restrict__ pr,
                                 float* __restrict__ o1) {
    __shared__ float lds_p[64][33];
    int lane = threadIdx.x & 63;
    int q = threadIdx.x >> 6;              // wave id 0..3
    int gp = blockIdx.x * 64 + lane;       // global pixel id (64 px per block)
    int b = gp >> 14;
    int pix = gp & (NPIX - 1);
    int i = pix >> 7, j = pix & 127;
    const float* xb = x + ((size_t)b * 32) * 65536;

    float k1[9];
    const float* kp = kb + ((size_t)b * 9) * NPIX + pix;
#pragma unroll
    for (int r = 0; r < 9; ++r) k1[r] = kp[(size_t)r * NPIX];

    int y0 = 2 * i - 1;
    int coff = (j == 0) ? 0 : (2 * j - 2);
#pragma unroll
    for (int mg = 0; mg < 8; mg += 2) {
        float2 lo[2][3], hi[2][3];
#pragma unroll
        for (int mm = 0; mm < 2; ++mm) {
            const float* cb = xb + (size_t)(8 * q + mg + mm) * 65536;
#pragma unroll
            for (int ky = 0; ky < 3; ++ky) {
                int y = y0 + ky;
                int yc = y < 0 ? 0 : y;
                const float* row = cb + (size_t)yc * 256;
                lo[mm][ky] = *(const float2*)(row + coff);
                hi[mm][ky] = *(const float2*)(row + 2 * j);
            }
        }
#pragma unroll
        for (int mm = 0; mm < 2; ++mm) {
            float acc = 0.f;
#pragma unroll
            for (int ky = 0; ky < 3; ++ky) {
                int y = y0 + ky;
                float t0 = (j == 0) ? 0.f : lo[mm][ky].y;
                float t1 = hi[mm][ky].x;
                float t2 = hi[mm][ky].y;
                if (y < 0) { t0 = 0.f; t1 = 0.f; t2 = 0.f; }
                acc = fmaf(k1[3 * ky + 0], t0, acc);
                acc = fmaf(k1[3 * ky + 1], t1, acc);
                acc = fmaf(k1[3 * ky + 2], t2, acc);
            }
            lds_p[lane][8 * q + mg + mm] = acc;
        }
    }
    __syncthreads();

    float pv[32];
#pragma unroll
    for (int m = 0; m < 32; ++m) pv[m] = lds_p[lane][m];
    float* ob = o1 + ((size_t)b * 64) * NPIX + pix;
#pragma unroll
    for (int cc = 0; cc < 16; ++cc) {
        int c = 16 * q + cc;
        const float* wc = w + c * 32;
        float a0 = 0.f, a1 = 0.f, a2 = 0.f, a3 = 0.f;
#pragma unroll
        for (int m = 0; m < 32; m += 4) {
            float4 w4 = *(const float4*)(wc + m);
            a0 = fmaf(w4.x, pv[m + 0], a0);
            a1 = fmaf(w4.y, pv[m + 1], a1);
            a2 = fmaf(w4.z, pv[m + 2], a2);
            a3 = fmaf(w4.w, pv[m + 3], a3);
        }
        float sc = g[c] * rsqrtf(vr[c] + 1e-3f);
        float v = ((a0 + a1) + (a2 + a3) - mn[c]) * sc + bt[c];
        v = v > 0.f ? v : pr[c] * v;
        ob[(size_t)c * NPIX] = v;
    }
}

// ---------------- c-split streamed kernel-gen for dilated stages
// [= dstage phase 1, correctness-proven in R6; no big arrays -> no spill]
// Block = (stage s, batch b, 64-px half-row); thread = (pixel lane, c-quarter q).
// o1 (B,64,NPIX) -> k5 (5,B,9,NPIX)
__global__ void kgen5cs_kernel(const float* __restrict__ o1,
                               const float* __restrict__ wrpT,   // (5,64,64) [s][m][c]
                               const float* __restrict__ bp,     // (5,64)
                               const float* __restrict__ wspan5, // (5,9,64)
                               float* __restrict__ kout) {
    __shared__ float pk_lds[9][4][66];
    int blk = blockIdx.x;                  // 10240 = 8 XCD chunks * 1280
    int v = (blk & 7) * 1280 + (blk >> 3); // contiguous v within an XCD
    int s = v >> 11;                       // stage 0..4
    int b = (v >> 8) & 7;
    int chunk = v & 255;                   // 64-px half-row
    int i = chunk >> 1;
    int lane = threadIdx.x & 63;
    int q = threadIdx.x >> 6;              // c-quarter 0..3
    int j = ((chunk & 1) << 6) + lane;
    int pix = i * 128 + j;
    const float* ob = o1 + ((size_t)b * 64) * NPIX + pix;

    // acc[16] = bp + sum_m wrpT[m][c]*o1[m]  (streamed, ~50 live VGPRs)
    float acc[16];
    {
        const float* bpc = bp + s * 64 + 16 * q;
        float4 b0 = *(const float4*)(bpc + 0);
        float4 b1 = *(const float4*)(bpc + 4);
        float4 b2 = *(const float4*)(bpc + 8);
        float4 b3 = *(const float4*)(bpc + 12);
        acc[0] = b0.x; acc[1] = b0.y; acc[2] = b0.z; acc[3] = b0.w;
        acc[4] = b1.x; acc[5] = b1.y; acc[6] = b1.z; acc[7] = b1.w;
        acc[8] = b2.x; acc[9] = b2.y; acc[10] = b2.z; acc[11] = b2.w;
        acc[12] = b3.x; acc[13] = b3.y; acc[14] = b3.z; acc[15] = b3.w;
    }
    const float* wT = wrpT + (size_t)s * 4096 + 16 * q;
#pragma unroll 8
    for (int m = 0; m < 64; ++m) {
        float vv = ob[(size_t)m * NPIX];
        const float* wm = wT + m * 64;
        float4 w0 = *(const float4*)(wm + 0);
        float4 w1 = *(const float4*)(wm + 4);
        float4 w2 = *(const float4*)(wm + 8);
        float4 w3 = *(const float4*)(wm + 12);
        acc[0]  = fmaf(w0.x, vv, acc[0]);  acc[1]  = fmaf(w0.y, vv, acc[1]);
        acc[2]  = fmaf(w0.z, vv, acc[2]);  acc[3]  = fmaf(w0.w, vv, acc[3]);
        acc[4]  = fmaf(w1.x, vv, acc[4]);  acc[5]  = fmaf(w1.y, vv, acc[5]);
        acc[6]  = fmaf(w1.z, vv, acc[6]);  acc[7]  = fmaf(w1.w, vv, acc[7]);
        acc[8]  = fmaf(w2.x, vv, acc[8]);  acc[9]  = fmaf(w2.y, vv, acc[9]);
        acc[10] = fmaf(w2.z, vv, acc[10]); acc[11] = fmaf(w2.w, vv, acc[11]);
        acc[12] = fmaf(w3.x, vv, acc[12]); acc[13] = fmaf(w3.y, vv, acc[13]);
        acc[14] = fmaf(w3.z, vv, acc[14]); acc[15] = fmaf(w3.w, vv, acc[15]);
    }
#pragma unroll
    for (int cc = 0; cc < 16; ++cc) acc[cc] = acc[cc] > 0.f ? acc[cc] : 0.f;

    // span partials over this quarter's 16 channels
    const float* wsp_s = wspan5 + s * 576 + 16 * q;
#pragma unroll
    for (int r = 0; r < 9; ++r) {
        const float* wr_ = wsp_s + r * 64;
        float4 w0 = *(const float4*)(wr_ + 0);
        float4 w1 = *(const float4*)(wr_ + 4);
        float4 w2 = *(const float4*)(wr_ + 8);
        float4 w3 = *(const float4*)(wr_ + 12);
        float p0 = fmaf(w0.x, acc[0], fmaf(w0.y, acc[1], fmaf(w0.z, acc[2], w0.w * acc[3])));
        float p1 = fmaf(w1.x, acc[4], fmaf(w1.y, acc[5], fmaf(w1.z, acc[6], w1.w * acc[7])));
        float p2 = fmaf(w2.x, acc[8], fmaf(w2.y, acc[9], fmaf(w2.z, acc[10], w2.w * acc[11])));
        float p3 = fmaf(w3.x, acc[12], fmaf(w3.y, acc[13], fmaf(w3.z, acc[14], w3.w * acc[15])));
        pk_lds[r][q][lane] = (p0 + p1) + (p2 + p3);
    }
    __syncthreads();

    // each wave writes its share of the 9 taps (coalesced 256B rows)
    float* ko = kout + ((size_t)(s * BATCH + b) * 9) * NPIX + pix;
#pragma unroll
    for (int r = q; r < 9; r += 4) {
        float kv = (pk_lds[r][0][lane] + pk_lds[r][1][lane]) +
                   (pk_lds[r][2][lane] + pk_lds[r][3][lane]);
        ko[(size_t)r * NPIX] = kv;
    }
}

// ---------------- fused dilated involution: one stage's 4-pixel tile [proven]
template <int DIL>
__device__ __forceinline__ void invo_tap4(const float* __restrict__ xp,
                                          const float* __restrict__ kp,
                                          int i, int j0, float acc[4]) {
    constexpr int LOFF = (DIL < 4) ? 4 : DIL;
    float xw[3][12];
#pragma unroll
    for (int ky = 0; ky < 3; ++ky) {
        int y = i + DIL * (ky - 1);
        int yc = ((unsigned)y < 128u) ? y : i;            // safe row for OOB (zeroed later)
        const float* row = xp + (size_t)yc * 128;
        *(float4*)&xw[ky][0] = *(const float4*)(row + j0 - LOFF);  // guard offset covers underflow
        *(float4*)&xw[ky][4] = *(const float4*)(row + j0);
        *(float4*)&xw[ky][8] = *(const float4*)(row + j0 + LOFF);
    }
    float kv[36];
#pragma unroll
    for (int r = 0; r < 9; ++r) *(float4*)&kv[4 * r] = *(const float4*)(kp + (size_t)r * NPIX);
#pragma unroll
    for (int ky = 0; ky < 3; ++ky) {
        int y = i + DIL * (ky - 1);
        bool yok = (unsigned)y < 128u;
#pragma unroll
        for (int kx = 0; kx < 3; ++kx) {
#pragma unroll
            for (int pp = 0; pp < 4; ++pp) {
                int xx = j0 + pp + DIL * (kx - 1);
                bool ok = yok && ((kx == 1) || ((unsigned)xx < 128u));
                int widx = 4 + pp + ((DIL < 4) ? DIL : 4) * (kx - 1);
                float xv = ok ? xw[ky][widx] : 0.f;
                acc[pp] = fmaf(xv, kv[4 * (3 * ky + kx) + pp], acc[pp]);
            }
        }
    }
}

__global__ void apply5_kernel(const float* __restrict__ o1, const float* __restrict__ kb, // (5,B,9,NPIX)
                              const float* __restrict__ gd5, const float* __restrict__ bd5,
                              const float* __restrict__ md5, const float* __restrict__ vd5,
                              const float* __restrict__ ad5,
                              const float* __restrict__ gf, const float* __restrict__ bf,
                              const float* __restrict__ mf, const float* __restrict__ vf,
                              const float* __restrict__ af,
                              float* __restrict__ out) {
    int blk = blockIdx.x;                                 // 16 bpsHi * 64c * 8 bpsLo
    int low3 = blk & 7;
    int c = (blk >> 3) & 63;
    int bps = (blk >> 9) * 8 + low3;
    int b = bps >> 4, ps = bps & 15;
    int pix0 = ps * 1024 + threadIdx.x * 4;
    int i = pix0 >> 7, j0 = pix0 & 127;
    const float* xp = o1 + ((size_t)(b * 64 + c)) * NPIX;

#define STAGE(S, D)                                                            \
    {                                                                          \
        float acc[4] = {0.f, 0.f, 0.f, 0.f};                                   \
        const float* kp = kb + ((size_t)(S * BATCH + b) * 9) * NPIX + pix0;    \
        invo_tap4<D>(xp, kp, i, j0, acc);                                      \
        int sc = S * 64 + c;                                                   \
        float scd = gd5[sc] * rsqrtf(vd5[sc] + 1e-3f);                         \
        float scf = gf[sc] * rsqrtf(vf[sc] + 1e-3f);                           \
        float4 o; float* op = (float*)&o;                                      \
        _Pragma("unroll")                                                      \
        for (int pp = 0; pp < 4; ++pp) {                                       \
            float v = (acc[pp] - md5[sc]) * scd + bd5[sc];                     \
            v = v > 0.f ? v : ad5[sc] * v;                                     \
            v = (v - mf[sc]) * scf + bf[sc];                                   \
            v = v > 0.f ? v : af[sc] * v;                                      \
            op[pp] = v;                                                       \
        }                                                                      \
        *(float4*)(out + ((size_t)(b * 320 + sc)) * NPIX + pix0) = o;          \
    }
    STAGE(0, 1)
    STAGE(1, 2)
    STAGE(2, 4)
    STAGE(3, 8)
    STAGE(4, 16)
#undef STAGE
}

extern "C" void kernel_launch(void* const* d_in, const int* in_sizes, int n_in,
                              void* d_out, int out_size, void* d_ws, size_t ws_size,
                              hipStream_t stream) {
    const float* x       = (const float*)d_in[0];
    const float* w1_init = (const float*)d_in[1];
    const float* w1_red  = (const float*)d_in[2];
    const float* s1_g    = (const float*)d_in[3];
    const float* s1_b    = (const float*)d_in[4];
    const float* s1_m    = (const float*)d_in[5];
    const float* s1_v    = (const float*)d_in[6];
    const float* w1_span = (const float*)d_in[7];
    const float* bn1_g   = (const float*)d_in[8];
    const float* bn1_b   = (const float*)d_in[9];
    const float* bn1_m   = (const float*)d_in[10];
    const float* bn1_v   = (const float*)d_in[11];
    const float* pr1     = (const float*)d_in[12];
    const float* wd_red  = (const float*)d_in[13];  // (5,64,64)
    const float* sd_g    = (const float*)d_in[14];
    const float* sd_b    = (const float*)d_in[15];
    const float* sd_m    = (const float*)d_in[16];
    const float* sd_v    = (const float*)d_in[17];
    const float* wd_span = (const float*)d_in[18];  // (5,9,64)
    const float* bnd_g   = (const float*)d_in[19];
    const float* bnd_b   = (const float*)d_in[20];
    const float* bnd_m   = (const float*)d_in[21];
    const float* bnd_v   = (const float*)d_in[22];
    const float* prd     = (const float*)d_in[23];
    const float* bnf_g   = (const float*)d_in[24];
    const float* bnf_b   = (const float*)d_in[25];
    const float* bnf_m   = (const float*)d_in[26];
    const float* bnf_v   = (const float*)d_in[27];
    const float* prf     = (const float*)d_in[28];
    float* out = (float*)d_out;

    float* ws    = (float*)d_ws;
    float* o1buf = ws + 64;                    // +64 guard floats for j0-LOFF underflow
    float* k1buf = o1buf + 8388608;            // 8*64*16384
    float* k5buf = k1buf + 1179648;            // 8*9*16384
    float* wrpT  = k5buf + 5898240;            // 5*8*9*16384
    float* bpbuf = wrpT + 20480;               // 5*64*64

    const int TB = 256;

    hipLaunchKernelGGL(prep_kernel, dim3(80), dim3(TB), 0, stream,
                       wd_red, sd_g, sd_b, sd_m, sd_v, wrpT, bpbuf);
    hipLaunchKernelGGL(kgen1_kernel, dim3(BATCH * NPIX / TB), dim3(TB), 0, stream,
                       x, w1_red, s1_g, s1_b, s1_m, s1_v, w1_span, k1buf);
    hipLaunchKernelGGL(applyconv_kernel, dim3(2048), dim3(TB), 0, stream,
                       x, k1buf, w1_init, bn1_g, bn1_b, bn1_m, bn1_v, pr1, o1buf);
    hipLaunchKernelGGL(kgen5cs_kernel, dim3(10240), dim3(TB), 0, stream,
                       o1buf, wrpT, bpbuf, wd_span, k5buf);
    hipLaunchKernelGGL(apply5_kernel, dim3(8192), dim3(TB), 0, stream,
                       o1buf, k5buf,
                       bnd_g, bnd_b, bnd_m, bnd_v, prd,
                       bnf_g, bnf_b, bnf_m, bnf_v, prf,
                       out);
}

// Round 8
// 457.732 us; speedup vs baseline: 1.9822x; 1.6656x over previous
//
#include <hip/hip_runtime.h>

#define NPIX 16384   // 128*128
#define BATCH 8

// ---------------- prep: fold bn(1e-5) into reduce weights + transpose
// wrpT[s][m][c] = wd_red[s][c][m] * scd(s,c);  bp[s][c] = sb - sm*scd
__global__ void prep_kernel(const float* __restrict__ wred5,   // (5,64,64)
                            const float* __restrict__ sg5, const float* __restrict__ sb5,
                            const float* __restrict__ sm5, const float* __restrict__ sv5,
                            float* __restrict__ wrpT,          // (5,64,64) [s][m][c]
                            float* __restrict__ bp) {          // (5,64)
    int t = blockIdx.x * blockDim.x + threadIdx.x;
    if (t >= 5 * 64 * 64) return;
    int s = t >> 12;
    int m = (t >> 6) & 63;
    int c = t & 63;
    int sc_i = s * 64 + c;
    float scd = sg5[sc_i] * rsqrtf(sv5[sc_i] + 1e-5f);
    wrpT[(size_t)s * 4096 + m * 64 + c] = wred5[(size_t)s * 4096 + c * 64 + m] * scd;
    if (m == 0) bp[sc_i] = sb5[sc_i] - sm5[sc_i] * scd;
}

// ---------------- stage-1 kernel generation with fused 2x2 avg-pool [proven]
__global__ void kgen1_kernel(const float* __restrict__ x,
                             const float* __restrict__ w_red,   // (32,32)
                             const float* __restrict__ g,
                             const float* __restrict__ bta,
                             const float* __restrict__ mn,
                             const float* __restrict__ vr,
                             const float* __restrict__ w_span,  // (9,32)
                             float* __restrict__ kout) {
    int t = blockIdx.x * blockDim.x + threadIdx.x;        // B*NPIX threads
    int b = t >> 14;
    int pix = t & (NPIX - 1);
    int j = pix & 127, i = pix >> 7;
    float inv[32];
    const float* xb = x + ((size_t)b * 32) * 65536 + (size_t)(2 * i) * 256 + 2 * j;
#pragma unroll
    for (int m = 0; m < 32; ++m) {
        const float2* r0 = (const float2*)(xb + (size_t)m * 65536);
        const float2* r1 = (const float2*)(xb + (size_t)m * 65536 + 256);
        float2 a = r0[0], bb = r1[0];
        inv[m] = 0.25f * ((a.x + a.y) + (bb.x + bb.y));
    }
    float kacc[9];
#pragma unroll
    for (int r = 0; r < 9; ++r) kacc[r] = 0.f;
    for (int c = 0; c < 32; ++c) {
        float a0 = 0.f, a1 = 0.f, a2 = 0.f, a3 = 0.f;
#pragma unroll
        for (int m = 0; m < 32; m += 4) {
            a0 = fmaf(w_red[c * 32 + m + 0], inv[m + 0], a0);
            a1 = fmaf(w_red[c * 32 + m + 1], inv[m + 1], a1);
            a2 = fmaf(w_red[c * 32 + m + 2], inv[m + 2], a2);
            a3 = fmaf(w_red[c * 32 + m + 3], inv[m + 3], a3);
        }
        float acc = (a0 + a1) + (a2 + a3);
        float sc = g[c] * rsqrtf(vr[c] + 1e-5f);
        float tt = (acc - mn[c]) * sc + bta[c];
        tt = tt > 0.f ? tt : 0.f;
#pragma unroll
        for (int r = 0; r < 9; ++r) kacc[r] = fmaf(w_span[r * 32 + c], tt, kacc[r]);
    }
    float* ko = kout + ((size_t)b * 9) * NPIX + pix;
#pragma unroll
    for (int r = 0; r < 9; ++r) ko[(size_t)r * NPIX] = kacc[r];
}

// ---------------- fused involution-apply + 1x1 conv 32->64 + bn + prelu [proven]
// Phase-C weight addressing hoisted to SGPR via readfirstlane (wave-uniform q).
__global__ void applyconv_kernel(const float* __restrict__ x,
                                 const float* __restrict__ kb,   // (B,9,NPIX)
                                 const float* __restrict__ w,    // (64,32) w1_init
                                 const float* __restrict__ g, const float* __restrict__ bt,
                                 const float* __restrict__ mn, const float* __restrict__ vr,
                                 const float* __restrict__ pr,
                                 float* __restrict__ o1) {
    __shared__ float lds_p[64][33];
    int lane = threadIdx.x & 63;
    int q = threadIdx.x >> 6;              // wave id 0..3 (wave-uniform in fact)
    int gp = blockIdx.x * 64 + lane;       // global pixel id (64 px per block)
    int b = gp >> 14;
    int pix = gp & (NPIX - 1);
    int i = pix >> 7, j = pix & 127;
    const float* xb = x + ((size_t)b * 32) * 65536;

    float k1[9];
    const float* kp = kb + ((size_t)b * 9) * NPIX + pix;
#pragma unroll
    for (int r = 0; r < 9; ++r) k1[r] = kp[(size_t)r * NPIX];

    int y0 = 2 * i - 1;
    int coff = (j == 0) ? 0 : (2 * j - 2);
#pragma unroll
    for (int mg = 0; mg < 8; mg += 2) {
        float2 lo[2][3], hi[2][3];
#pragma unroll
        for (int mm = 0; mm < 2; ++mm) {
            const float* cb = xb + (size_t)(8 * q + mg + mm) * 65536;
#pragma unroll
            for (int ky = 0; ky < 3; ++ky) {
                int y = y0 + ky;
                int yc = y < 0 ? 0 : y;
                const float* row = cb + (size_t)yc * 256;
                lo[mm][ky] = *(const float2*)(row + coff);
                hi[mm][ky] = *(const float2*)(row + 2 * j);
            }
        }
#pragma unroll
        for (int mm = 0; mm < 2; ++mm) {
            float acc = 0.f;
#pragma unroll
            for (int ky = 0; ky < 3; ++ky) {
                int y = y0 + ky;
                float t0 = (j == 0) ? 0.f : lo[mm][ky].y;
                float t1 = hi[mm][ky].x;
                float t2 = hi[mm][ky].y;
                if (y < 0) { t0 = 0.f; t1 = 0.f; t2 = 0.f; }
                acc = fmaf(k1[3 * ky + 0], t0, acc);
                acc = fmaf(k1[3 * ky + 1], t1, acc);
                acc = fmaf(k1[3 * ky + 2], t2, acc);
            }
            lds_p[lane][8 * q + mg + mm] = acc;
        }
    }
    __syncthreads();

    float pv[32];
#pragma unroll
    for (int m = 0; m < 32; ++m) pv[m] = lds_p[lane][m];
    float* ob = o1 + ((size_t)b * 64) * NPIX + pix;
    int qu = __builtin_amdgcn_readfirstlane(q);    // SGPR wave id -> s_load weights
#pragma unroll
    for (int cc = 0; cc < 16; ++cc) {
        int c = 16 * qu + cc;
        const float* wc = w + c * 32;
        float a0 = 0.f, a1 = 0.f, a2 = 0.f, a3 = 0.f;
#pragma unroll
        for (int m = 0; m < 32; m += 4) {
            float4 w4 = *(const float4*)(wc + m);
            a0 = fmaf(w4.x, pv[m + 0], a0);
            a1 = fmaf(w4.y, pv[m + 1], a1);
            a2 = fmaf(w4.z, pv[m + 2], a2);
            a3 = fmaf(w4.w, pv[m + 3], a3);
        }
        float sc = g[c] * rsqrtf(vr[c] + 1e-3f);
        float v = ((a0 + a1) + (a2 + a3) - mn[c]) * sc + bt[c];
        v = v > 0.f ? v : pr[c] * v;
        ob[(size_t)c * NPIX] = v;
    }
}

// ---------------- c-split streamed kernel-gen for dilated stages
// Weight/bias addresses hoisted to SGPR via readfirstlane(wave id) so the
// per-m weight reads become s_load (K$) instead of 4 per-lane vector loads.
// Block = (stage s, batch b, 64-px half-row); thread = (pixel lane, c-quarter q).
// o1 (B,64,NPIX) -> k5 (5,B,9,NPIX)
__global__ void kgen5cs_kernel(const float* __restrict__ o1,
                               const float* __restrict__ wrpT,   // (5,64,64) [s][m][c]
                               const float* __restrict__ bp,     // (5,64)
                               const float* __restrict__ wspan5, // (5,9,64)
                               float* __restrict__ kout) {
    __shared__ float pk_lds[9][4][66];
    int blk = blockIdx.x;                  // 10240 = 8 XCD chunks * 1280
    int v = (blk & 7) * 1280 + (blk >> 3); // contiguous v within an XCD
    int s = v >> 11;                       // stage 0..4
    int b = (v >> 8) & 7;
    int chunk = v & 255;                   // 64-px half-row
    int i = chunk >> 1;
    int lane = threadIdx.x & 63;
    int q = threadIdx.x >> 6;              // c-quarter 0..3 (wave-uniform in fact)
    int qu = __builtin_amdgcn_readfirstlane(q);   // SGPR copy for addressing
    int j = ((chunk & 1) << 6) + lane;
    int pix = i * 128 + j;
    const float* ob = o1 + ((size_t)b * 64) * NPIX + pix;

    // acc[16] = bp + sum_m wrpT[m][c]*o1[m]  (streamed; weights via s_load)
    float acc[16];
    {
        const float* bpc = bp + s * 64 + 16 * qu;
        float4 b0 = *(const float4*)(bpc + 0);
        float4 b1 = *(const float4*)(bpc + 4);
        float4 b2 = *(const float4*)(bpc + 8);
        float4 b3 = *(const float4*)(bpc + 12);
        acc[0] = b0.x; acc[1] = b0.y; acc[2] = b0.z; acc[3] = b0.w;
        acc[4] = b1.x; acc[5] = b1.y; acc[6] = b1.z; acc[7] = b1.w;
        acc[8] = b2.x; acc[9] = b2.y; acc[10] = b2.z; acc[11] = b2.w;
        acc[12] = b3.x; acc[13] = b3.y; acc[14] = b3.z; acc[15] = b3.w;
    }
    const float* wT = wrpT + (size_t)s * 4096 + 16 * qu;
#pragma unroll 8
    for (int m = 0; m < 64; ++m) {
        float vv = ob[(size_t)m * NPIX];
        const float* wm = wT + m * 64;
        float4 w0 = *(const float4*)(wm + 0);
        float4 w1 = *(const float4*)(wm + 4);
        float4 w2 = *(const float4*)(wm + 8);
        float4 w3 = *(const float4*)(wm + 12);
        acc[0]  = fmaf(w0.x, vv, acc[0]);  acc[1]  = fmaf(w0.y, vv, acc[1]);
        acc[2]  = fmaf(w0.z, vv, acc[2]);  acc[3]  = fmaf(w0.w, vv, acc[3]);
        acc[4]  = fmaf(w1.x, vv, acc[4]);  acc[5]  = fmaf(w1.y, vv, acc[5]);
        acc[6]  = fmaf(w1.z, vv, acc[6]);  acc[7]  = fmaf(w1.w, vv, acc[7]);
        acc[8]  = fmaf(w2.x, vv, acc[8]);  acc[9]  = fmaf(w2.y, vv, acc[9]);
        acc[10] = fmaf(w2.z, vv, acc[10]); acc[11] = fmaf(w2.w, vv, acc[11]);
        acc[12] = fmaf(w3.x, vv, acc[12]); acc[13] = fmaf(w3.y, vv, acc[13]);
        acc[14] = fmaf(w3.z, vv, acc[14]); acc[15] = fmaf(w3.w, vv, acc[15]);
    }
#pragma unroll
    for (int cc = 0; cc < 16; ++cc) acc[cc] = acc[cc] > 0.f ? acc[cc] : 0.f;

    // span partials over this quarter's 16 channels (weights via s_load)
    const float* wsp_s = wspan5 + s * 576 + 16 * qu;
#pragma unroll
    for (int r = 0; r < 9; ++r) {
        const float* wr_ = wsp_s + r * 64;
        float4 w0 = *(const float4*)(wr_ + 0);
        float4 w1 = *(const float4*)(wr_ + 4);
        float4 w2 = *(const float4*)(wr_ + 8);
        float4 w3 = *(const float4*)(wr_ + 12);
        float p0 = fmaf(w0.x, acc[0], fmaf(w0.y, acc[1], fmaf(w0.z, acc[2], w0.w * acc[3])));
        float p1 = fmaf(w1.x, acc[4], fmaf(w1.y, acc[5], fmaf(w1.z, acc[6], w1.w * acc[7])));
        float p2 = fmaf(w2.x, acc[8], fmaf(w2.y, acc[9], fmaf(w2.z, acc[10], w2.w * acc[11])));
        float p3 = fmaf(w3.x, acc[12], fmaf(w3.y, acc[13], fmaf(w3.z, acc[14], w3.w * acc[15])));
        pk_lds[r][q][lane] = (p0 + p1) + (p2 + p3);
    }
    __syncthreads();

    // each wave writes its share of the 9 taps (coalesced 256B rows)
    float* ko = kout + ((size_t)(s * BATCH + b) * 9) * NPIX + pix;
#pragma unroll
    for (int r = q; r < 9; r += 4) {
        float kv = (pk_lds[r][0][lane] + pk_lds[r][1][lane]) +
                   (pk_lds[r][2][lane] + pk_lds[r][3][lane]);
        ko[(size_t)r * NPIX] = kv;
    }
}

// ---------------- fused dilated involution: one stage's 4-pixel tile [proven]
template <int DIL>
__device__ __forceinline__ void invo_tap4(const float* __restrict__ xp,
                                          const float* __restrict__ kp,
                                          int i, int j0, float acc[4]) {
    constexpr int LOFF = (DIL < 4) ? 4 : DIL;
    float xw[3][12];
#pragma unroll
    for (int ky = 0; ky < 3; ++ky) {
        int y = i + DIL * (ky - 1);
        int yc = ((unsigned)y < 128u) ? y : i;            // safe row for OOB (zeroed later)
        const float* row = xp + (size_t)yc * 128;
        *(float4*)&xw[ky][0] = *(const float4*)(row + j0 - LOFF);  // guard offset covers underflow
        *(float4*)&xw[ky][4] = *(const float4*)(row + j0);
        *(float4*)&xw[ky][8] = *(const float4*)(row + j0 + LOFF);
    }
    float kv[36];
#pragma unroll
    for (int r = 0; r < 9; ++r) *(float4*)&kv[4 * r] = *(const float4*)(kp + (size_t)r * NPIX);
#pragma unroll
    for (int ky = 0; ky < 3; ++ky) {
        int y = i + DIL * (ky - 1);
        bool yok = (unsigned)y < 128u;
#pragma unroll
        for (int kx = 0; kx < 3; ++kx) {
#pragma unroll
            for (int pp = 0; pp < 4; ++pp) {
                int xx = j0 + pp + DIL * (kx - 1);
                bool ok = yok && ((kx == 1) || ((unsigned)xx < 128u));
                int widx = 4 + pp + ((DIL < 4) ? DIL : 4) * (kx - 1);
                float xv = ok ? xw[ky][widx] : 0.f;
                acc[pp] = fmaf(xv, kv[4 * (3 * ky + kx) + pp], acc[pp]);
            }
        }
    }
}

__global__ void apply5_kernel(const float* __restrict__ o1, const float* __restrict__ kb, // (5,B,9,NPIX)
                              const float* __restrict__ gd5, const float* __restrict__ bd5,
                              const float* __restrict__ md5, const float* __restrict__ vd5,
                              const float* __restrict__ ad5,
                              const float* __restrict__ gf, const float* __restrict__ bf,
                              const float* __restrict__ mf, const float* __restrict__ vf,
                              const float* __restrict__ af,
                              float* __restrict__ out) {
    int blk = blockIdx.x;                                 // 16 bpsHi * 64c * 8 bpsLo
    int low3 = blk & 7;
    int c = (blk >> 3) & 63;
    int bps = (blk >> 9) * 8 + low3;
    int b = bps >> 4, ps = bps & 15;
    int pix0 = ps * 1024 + threadIdx.x * 4;
    int i = pix0 >> 7, j0 = pix0 & 127;
    const float* xp = o1 + ((size_t)(b * 64 + c)) * NPIX;

#define STAGE(S, D)                                                            \
    {                                                                          \
        float acc[4] = {0.f, 0.f, 0.f, 0.f};                                   \
        const float* kp = kb + ((size_t)(S * BATCH + b) * 9) * NPIX + pix0;    \
        invo_tap4<D>(xp, kp, i, j0, acc);                                      \
        int sc = S * 64 + c;                                                   \
        float scd = gd5[sc] * rsqrtf(vd5[sc] + 1e-3f);                         \
        float scf = gf[sc] * rsqrtf(vf[sc] + 1e-3f);                           \
        float4 o; float* op = (float*)&o;                                      \
        _Pragma("unroll")                                                      \
        for (int pp = 0; pp < 4; ++pp) {                                       \
            float v = (acc[pp] - md5[sc]) * scd + bd5[sc];                     \
            v = v > 0.f ? v : ad5[sc] * v;                                     \
            v = (v - mf[sc]) * scf + bf[sc];                                   \
            v = v > 0.f ? v : af[sc] * v;                                      \
            op[pp] = v;                                                       \
        }                                                                      \
        *(float4*)(out + ((size_t)(b * 320 + sc)) * NPIX + pix0) = o;          \
    }
    STAGE(0, 1)
    STAGE(1, 2)
    STAGE(2, 4)
    STAGE(3, 8)
    STAGE(4, 16)
#undef STAGE
}

extern "C" void kernel_launch(void* const* d_in, const int* in_sizes, int n_in,
                              void* d_out, int out_size, void* d_ws, size_t ws_size,
                              hipStream_t stream) {
    const float* x       = (const float*)d_in[0];
    const float* w1_init = (const float*)d_in[1];
    const float* w1_red  = (const float*)d_in[2];
    const float* s1_g    = (const float*)d_in[3];
    const float* s1_b    = (const float*)d_in[4];
    const float* s1_m    = (const float*)d_in[5];
    const float* s1_v    = (const float*)d_in[6];
    const float* w1_span = (const float*)d_in[7];
    const float* bn1_g   = (const float*)d_in[8];
    const float* bn1_b   = (const float*)d_in[9];
    const float* bn1_m   = (const float*)d_in[10];
    const float* bn1_v   = (const float*)d_in[11];
    const float* pr1     = (const float*)d_in[12];
    const float* wd_red  = (const float*)d_in[13];  // (5,64,64)
    const float* sd_g    = (const float*)d_in[14];
    const float* sd_b    = (const float*)d_in[15];
    const float* sd_m    = (const float*)d_in[16];
    const float* sd_v    = (const float*)d_in[17];
    const float* wd_span = (const float*)d_in[18];  // (5,9,64)
    const float* bnd_g   = (const float*)d_in[19];
    const float* bnd_b   = (const float*)d_in[20];
    const float* bnd_m   = (const float*)d_in[21];
    const float* bnd_v   = (const float*)d_in[22];
    const float* prd     = (const float*)d_in[23];
    const float* bnf_g   = (const float*)d_in[24];
    const float* bnf_b   = (const float*)d_in[25];
    const float* bnf_m   = (const float*)d_in[26];
    const float* bnf_v   = (const float*)d_in[27];
    const float* prf     = (const float*)d_in[28];
    float* out = (float*)d_out;

    float* ws    = (float*)d_ws;
    float* o1buf = ws + 64;                    // +64 guard floats for j0-LOFF underflow
    float* k1buf = o1buf + 8388608;            // 8*64*16384
    float* k5buf = k1buf + 1179648;            // 8*9*16384
    float* wrpT  = k5buf + 5898240;            // 5*8*9*16384
    float* bpbuf = wrpT + 20480;               // 5*64*64

    const int TB = 256;

    hipLaunchKernelGGL(prep_kernel, dim3(80), dim3(TB), 0, stream,
                       wd_red, sd_g, sd_b, sd_m, sd_v, wrpT, bpbuf);
    hipLaunchKernelGGL(kgen1_kernel, dim3(BATCH * NPIX / TB), dim3(TB), 0, stream,
                       x, w1_red, s1_g, s1_b, s1_m, s1_v, w1_span, k1buf);
    hipLaunchKernelGGL(applyconv_kernel, dim3(2048), dim3(TB), 0, stream,
                       x, k1buf, w1_init, bn1_g, bn1_b, bn1_m, bn1_v, pr1, o1buf);
    hipLaunchKernelGGL(kgen5cs_kernel, dim3(10240), dim3(TB), 0, stream,
                       o1buf, wrpT, bpbuf, wd_span, k5buf);
    hipLaunchKernelGGL(apply5_kernel, dim3(8192), dim3(TB), 0, stream,
                       o1buf, k5buf,
                       bnd_g, bnd_b, bnd_m, bnd_v, prd,
                       bnf_g, bnf_b, bnf_m, bnf_v, prf,
                       out);
}